// Round 14
// baseline (815.794 us; speedup 1.0000x reference)
//
#include <hip/hip_runtime.h>

#define PI_D 3.14159265358979323846

// Layouts
//  x[l2,part]: (8192, 15, l2+1, 5, 16) fp32  n-stride = 1200*(l2+1)
//  w[l1,part]: (l1+1, 15, 5, 16, 16)  fp32
//  b[l,part]:  (1, l+1, 5, 16)        fp32
//  out[l,part]:(8192, l+1, 5, 16) concat; base = 655360*(l+1)*(l+part)
// K (4800): l2{partp{kx{t{i16}}}}; kb offsets 0,30,90,180. col (320): l{part{lr{j16}}}
// ws: G @0 (64KB); W3 @64KB fragment-major bf16 (15.36MB):
//   W3[(((cw*5+p)*75+kt)*2+ks)*512 + lane*8 + b8] =
//     foldedW(p, col=cw*16+(lane&15), K=kt*64+ks*32+(lane>>4)*8+b8)
// FUSED gemm: block = 32 rows x 64 cols(cg) x ALL 5 p; A read directly from x
// in contiguous 320-B runs (kb = 5p x 16i consecutive floats); 5 cg-blocks of
// one n-tile adjacent on same XCD -> L2 dedupes the 5x A re-read. No pack.

typedef __attribute__((ext_vector_type(8))) short short8;
typedef __attribute__((ext_vector_type(4))) float f32x4;

struct Ptrs8 { const float* p[8]; };

__device__ __forceinline__ ushort f2bf(float x){
  uint u = __float_as_uint(x);
  return (ushort)((u + 0x7fffu + ((u>>16)&1u)) >> 16);
}

__device__ __forceinline__ double dfact(int n){ double r=1.0; for(int i=2;i<=n;++i) r*=(double)i; return r; }

__device__ double cg_coef(int j1,int m1,int j2,int m2,int j3,int m3){
  if(m1+m2!=m3) return 0.0;
  if(j3<abs(j1-j2)||j3>j1+j2) return 0.0;
  if(abs(m1)>j1||abs(m2)>j2||abs(m3)>j3) return 0.0;
  double pre = sqrt((2.0*j3+1.0)*dfact(j3+j1-j2)*dfact(j3-j1+j2)*dfact(j1+j2-j3)/dfact(j1+j2+j3+1));
  pre *= sqrt(dfact(j3+m3)*dfact(j3-m3)*dfact(j1-m1)*dfact(j1+m1)*dfact(j2-m2)*dfact(j2+m2));
  int kmin = max(0,max(j2-j3-m1,j1-j3+m2));
  int kmax = min(j1+j2-j3,min(j1-m1,j2+m2));
  double s=0.0;
  for(int k=kmin;k<=kmax;++k){
    double d = dfact(k)*dfact(j1+j2-j3-k)*dfact(j1-m1-k)*dfact(j2+m2-k)*dfact(j3-j2+m1+k)*dfact(j3-j1-m2+k);
    s += ((k&1)?-1.0:1.0)/d;
  }
  return pre*s;
}

__device__ __forceinline__ int gidx(int l,int l2,int combo,int lr,int kx,int l1,int m){
  return ((((((l*4+l2)*4+combo)*4+lr)*4+kx)*4+l1)*4+m);
}

__global__ void g_kernel(float* __restrict__ G){
  int tid = threadIdx.x;
  for(int e=tid;e<16384;e+=blockDim.x) G[e]=0.0f;
  __syncthreads();
  int trip = tid >> 4;
  int sub  = tid & 15;
  int lr = sub >> 2, m = sub & 3;
  int idx=0;
  for(int l=0;l<4;l++)for(int l1=0;l1<4;l1++){
    int lo=abs(l-l1), hi=min(3,l+l1);
    for(int l2=lo;l2<=hi;l2++){
      if(idx==trip && lr<=l && m<=l1){
        double c = 8.0*PI_D*PI_D/(2.0*l1+1.0)
                 * sqrt((2.0*l+1.0)*(2.0*l1+1.0)/(4.0*PI_D*(2.0*l2+1.0)))
                 * cg_coef(l,0,l1,0,l2,0);
        if(lr+m<=l2){
          float f = (float)(c * cg_coef(l,lr,l1,m,l2,lr+m) * ((m&1)?-1.0:1.0));
          G[gidx(l,l2,0,lr,lr+m,l1,m)] += f;
          G[gidx(l,l2,1,lr,lr+m,l1,m)] -= f;
          G[gidx(l,l2,2,lr,lr+m,l1,m)] += f;
          G[gidx(l,l2,3,lr,lr+m,l1,m)] += f;
        }
        if(m>0 && abs(lr-m)<=l2){
          if(lr-m>=0){
            float f = (float)(c * cg_coef(l,lr,l1,-m,l2,lr-m) * ((l1&1)?-1.0:1.0));
            G[gidx(l,l2,0,lr,lr-m,l1,m)] += f;
            G[gidx(l,l2,1,lr,lr-m,l1,m)] += f;
            G[gidx(l,l2,2,lr,lr-m,l1,m)] -= f;
            G[gidx(l,l2,3,lr,lr-m,l1,m)] += f;
          } else {
            float f = (float)(c * (((m-lr)&1)?-1.0:1.0) * (((l1+l2)&1)?-1.0:1.0)
                              * cg_coef(l,lr,l1,-m,l2,lr-m));
            G[gidx(l,l2,0,lr,m-lr,l1,m)] += f;
            G[gidx(l,l2,1,lr,m-lr,l1,m)] -= f;
            G[gidx(l,l2,2,lr,m-lr,l1,m)] -= f;
            G[gidx(l,l2,3,lr,m-lr,l1,m)] -= f;
          }
        }
      }
      idx++;
    }
  }
}

__device__ __forceinline__ void decode_kb(int kb,int& l2,int& partp,int& kx,int& t){
  int kbo;
  if(kb<30){l2=0;kbo=0;} else if(kb<90){l2=1;kbo=30;} else if(kb<180){l2=2;kbo=90;} else {l2=3;kbo=180;}
  int rem = kb-kbo;
  int per = (l2+1)*15;
  partp = rem/per;
  int q = rem%per;
  kx = q/15; t = q%15;
}

__device__ __forceinline__ void decode_col(int col,int& l,int& part,int& lr,int& j){
  int co;
  if(col<32){l=0;co=0;} else if(col<96){l=1;co=32;} else if(col<192){l=2;co=96;} else {l=3;co=192;}
  int cr = col-co; int per=(l+1)*16;
  part = cr/per; int q = cr%per; lr = q>>4; j = q&15;
}

// W3: fragment-major (see header)
__global__ void w3_kernel(const float* __restrict__ G, Ptrs8 wp, ushort* __restrict__ W3){
  long e = (long)blockIdx.x*256 + threadIdx.x;
  if(e >= 7680000L) return;
  int b8 = (int)(e & 7);
  int ln = (int)((e>>3) & 63);
  int ks = (int)((e>>9) & 1);
  int kt = (int)((e>>10) % 75);
  long rr = (e>>10) / 75;            // cw*5+p
  int p  = (int)(rr % 5);
  int cw = (int)(rr / 5);
  int col = cw*16 + (ln&15);
  int K = kt*64 + ks*32 + ((ln>>4)<<3) + b8;
  int i = K & 15; int kb = K >> 4;
  int l2,partp,kx,t; decode_kb(kb,l2,partp,kx,t);
  int l,part,lr,j; decode_col(col,l,part,lr,j);
  int combo = (part==0) ? (partp==0?0:1) : (partp==0?2:3);
  int wpart = (combo==0||combo==3)?0:1;
  int mstart = wpart?1:0;
  int woff = t*1280 + p*256 + i*16 + j;
  float acc=0.f;
  for(int l1=0;l1<4;l1++){
    const float* wptr = wp.p[l1*2+wpart];
    int gb = ((((l*4+l2)*4+combo)*4+lr)*4+kx)*16 + l1*4;
    for(int m=mstart;m<=l1;m++){
      float g = G[gb+m];
      if(g!=0.f) acc += g * wptr[m*19200 + woff];
    }
  }
  W3[e] = f2bf(acc);
}

// ---------------- FUSED GEMM --------------------------------------------------
// grid 1280 = 8 xcd x (32 nb_local x 5 cg); block 256 = 4 waves.
// Tile: 32 rows x 64 cols x 5 p. LDS A: [2][32 rows][5 p][72] ushorts
// (64 K-elems in 8 XOR-swizzled 16-B slots + 8 pad). KTB: 300-entry addr table.

__global__ __launch_bounds__(256,3) void gemm_fused(Ptrs8 xp, const ushort* __restrict__ W3,
                                                    Ptrs8 bp, float* __restrict__ out){
  __shared__ ushort As[2][11520];    // 32*5*72
  __shared__ int4 KTB[300];          // {ptr_lo, ptr_hi, byte_off, byte_nstride}
  const int tid = threadIdx.x;
  const int lane = tid & 63;
  const int w = tid >> 6;
  int orig = blockIdx.x;
  int xcd = orig & 7, q = orig >> 3;       // q in [0,160)
  const int nb = xcd*32 + q/5;             // 5 cg of same nb adjacent on one XCD
  const int cg = q % 5;
  const int n0 = nb*32;
  const int cw = cg*4 + w;
  const ushort* Wtw = W3 + (long)cw*5*75*1024;

  // fill kb -> address table
  for(int e=tid; e<300; e+=256){
    int l2,partp,kx,t; decode_kb(e,l2,partp,kx,t);
    const float* bptr = xp.p[l2*2+partp];
    KTB[e] = make_int4((int)(uint)(unsigned long long)bptr,
                       (int)((unsigned long long)bptr>>32),
                       ((t*(l2+1)+kx)*80)*4, (1200*(l2+1))*4);
  }

  // staging assignments: a = rd*256+tid in [0,640): (row32, kbl4, p5), p inner
  int srow[3], skbl[3], sp5[3]; bool sact[3];
  #pragma unroll
  for(int rd=0;rd<3;rd++){
    int a = rd*256 + tid;
    sact[rd] = a < 640;
    int aa = sact[rd] ? a : 0;
    srow[rd] = aa/20; int kbp = aa%20; skbl[rd] = kbp/5; sp5[rd] = kbp%5;
  }

  f32x4 acc[2][5] = {};
  float4 sv0[4], sv1[4], sv2[4];

  __syncthreads();   // KTB ready

#define STAGE_LD(kt, SV, rd) do { \
    if(sact[rd]){ \
      int4 tb = KTB[(kt)*4 + skbl[rd]]; \
      const char* src = (const char*)(((unsigned long long)(uint)tb.x) | ((unsigned long long)(uint)tb.y<<32)) \
                      + (long)(n0+srow[rd])*tb.w + tb.z + sp5[rd]*64; \
      _Pragma("unroll") \
      for(int c=0;c<4;c++) SV[c] = ((const float4*)src)[c]; \
    } \
  } while(0)

#define STAGE_ST(buf, SV, rd) do { \
    if(sact[rd]){ \
      uint u[8]; \
      _Pragma("unroll") \
      for(int c=0;c<4;c++){ \
        asm("v_cvt_pk_bf16_f32 %0, %1, %2" : "=v"(u[c*2])   : "v"(SV[c].x), "v"(SV[c].y)); \
        asm("v_cvt_pk_bf16_f32 %0, %1, %2" : "=v"(u[c*2+1]) : "v"(SV[c].z), "v"(SV[c].w)); \
      } \
      int row=srow[rd], bse = row*360 + sp5[rd]*72, rs = row&7; \
      uint4 w0; w0.x=u[0]; w0.y=u[1]; w0.z=u[2]; w0.w=u[3]; \
      uint4 w1; w1.x=u[4]; w1.y=u[5]; w1.z=u[6]; w1.w=u[7]; \
      *(uint4*)((buf) + bse + (((skbl[rd]*2)  )^rs)*8) = w0; \
      *(uint4*)((buf) + bse + (((skbl[rd]*2)+1)^rs)*8) = w1; \
    } \
  } while(0)

#define DO_TILE(A, kt) do { \
    _Pragma("unroll") \
    for(int p=0;p<5;p++){ \
      const ushort* wq = Wtw + ((long)p*75 + (kt))*1024 + lane*8; \
      short8 b0 = *(const short8*)(wq); \
      short8 b1 = *(const short8*)(wq + 512); \
      _Pragma("unroll") \
      for(int mi=0;mi<2;mi++){ \
        int row = mi*16 + (lane&15); \
        int bse = row*360 + p*72, rs = row&7; \
        short8 a0 = *(const short8*)((A) + bse + (((lane>>4)  )^rs)*8); \
        short8 a1 = *(const short8*)((A) + bse + ((4+(lane>>4))^rs)*8); \
        acc[mi][p] = __builtin_amdgcn_mfma_f32_16x16x32_bf16(a0, b0, acc[mi][p], 0,0,0); \
        acc[mi][p] = __builtin_amdgcn_mfma_f32_16x16x32_bf16(a1, b1, acc[mi][p], 0,0,0); \
      } \
    } \
  } while(0)

  // prologue: tile 0
  STAGE_LD(0, sv0, 0); STAGE_LD(0, sv1, 1); STAGE_LD(0, sv2, 2);
  STAGE_ST(&As[0][0], sv0, 0); STAGE_ST(&As[0][0], sv1, 1); STAGE_ST(&As[0][0], sv2, 2);
  __syncthreads();

  int buf = 0;
  #pragma unroll 1
  for(int kt=0;kt<74;++kt){
    STAGE_LD(kt+1, sv0, 0); STAGE_LD(kt+1, sv1, 1); STAGE_LD(kt+1, sv2, 2);  // HBM, contiguous
    DO_TILE(&As[buf][0], kt);                                                // MFMA + B(L2)
    STAGE_ST(&As[buf^1][0], sv0, 0); STAGE_ST(&As[buf^1][0], sv1, 1); STAGE_ST(&As[buf^1][0], sv2, 2);
    __syncthreads();
    buf ^= 1;
  }
  DO_TILE(&As[buf][0], 74);

  // epilogue: wave's cols = cw*16 + j, all 5 p
  int j = lane & 15, rg = (lane>>4)*4;
  int l, part, lr;
  if(cw<2){l=0;part=cw;lr=0;}
  else if(cw<6){int c=cw-2;l=1;part=c>>1;lr=c&1;}
  else if(cw<12){int c=cw-6;l=2;part=(c>=3);lr=part?(c-3):c;}
  else {int c=cw-12;l=3;part=c>>2;lr=c&3;}
  long base = 655360L*(l+1)*(l+part);
  int nst = (l+1)*80;
  #pragma unroll
  for(int p=0;p<5;p++){
    float bv = 0.f;
    if(!(part==1 && lr==0)) bv = bp.p[l*2+part][lr*80 + p*16 + j];
    long ioff = base + lr*80 + p*16 + j;
    #pragma unroll
    for(int mi=0;mi<2;++mi){
      int n = n0 + mi*16 + rg;
      #pragma unroll
      for(int r=0;r<4;++r)
        out[ioff + (long)(n+r)*nst] = acc[mi][p][r] + bv;
    }
  }
#undef STAGE_LD
#undef STAGE_ST
#undef DO_TILE
}

extern "C" void kernel_launch(void* const* d_in, const int* in_sizes, int n_in,
                              void* d_out, int out_size, void* d_ws, size_t ws_size,
                              hipStream_t stream){
  Ptrs8 xp, wp, bp;
  for(int i=0;i<8;i++){
    xp.p[i] = (const float*)d_in[i];
    wp.p[i] = (const float*)d_in[8+i];
    bp.p[i] = (const float*)d_in[16+i];
  }
  float* G = (float*)d_ws;
  ushort* W3 = (ushort*)((char*)d_ws + 65536);
  g_kernel<<<dim3(1), dim3(576), 0, stream>>>(G);
  w3_kernel<<<dim3(30000), dim3(256), 0, stream>>>(G, wp, W3);
  gemm_fused<<<dim3(1280), dim3(256), 0, stream>>>(xp, W3, bp, (float*)d_out);
}

// Round 15
// 552.148 us; speedup vs baseline: 1.4775x; 1.4775x over previous
//
#include <hip/hip_runtime.h>

#define PI_D 3.14159265358979323846

// Layouts
//  x[l2,part]: (8192, 15, l2+1, 5, 16) fp32  n-stride = 1200*(l2+1)
//  w[l1,part]: (l1+1, 15, 5, 16, 16)  fp32
//  b[l,part]:  (1, l+1, 5, 16)        fp32
//  out[l,part]:(8192, l+1, 5, 16) concat; base = 655360*(l+1)*(l+part)
// K (4800): l2{partp{kx{t{i16}}}}; kb offsets 0,30,90,180. col (320): l{part{lr{j16}}}
// ws: G @0 (64KB); W2 @64KB fragment-major bf16 (15.36MB);
//     Xp5 @16MB: [p][nb128][kt75][row64][slot8][16B] bf16 (393MB),
//     slot = c8 ^ (row&7)  (read-side LDS swizzle baked in).

typedef __attribute__((ext_vector_type(8))) short short8;
typedef __attribute__((ext_vector_type(4))) float f32x4;

struct Ptrs8 { const float* p[8]; };

__device__ __forceinline__ ushort f2bf(float x){
  uint u = __float_as_uint(x);
  return (ushort)((u + 0x7fffu + ((u>>16)&1u)) >> 16);
}

__device__ __forceinline__ double dfact(int n){ double r=1.0; for(int i=2;i<=n;++i) r*=(double)i; return r; }

__device__ double cg_coef(int j1,int m1,int j2,int m2,int j3,int m3){
  if(m1+m2!=m3) return 0.0;
  if(j3<abs(j1-j2)||j3>j1+j2) return 0.0;
  if(abs(m1)>j1||abs(m2)>j2||abs(m3)>j3) return 0.0;
  double pre = sqrt((2.0*j3+1.0)*dfact(j3+j1-j2)*dfact(j3-j1+j2)*dfact(j1+j2-j3)/dfact(j1+j2+j3+1));
  pre *= sqrt(dfact(j3+m3)*dfact(j3-m3)*dfact(j1-m1)*dfact(j1+m1)*dfact(j2-m2)*dfact(j2+m2));
  int kmin = max(0,max(j2-j3-m1,j1-j3+m2));
  int kmax = min(j1+j2-j3,min(j1-m1,j2+m2));
  double s=0.0;
  for(int k=kmin;k<=kmax;++k){
    double d = dfact(k)*dfact(j1+j2-j3-k)*dfact(j1-m1-k)*dfact(j2+m2-k)*dfact(j3-j2+m1+k)*dfact(j3-j1-m2+k);
    s += ((k&1)?-1.0:1.0)/d;
  }
  return pre*s;
}

__device__ __forceinline__ int gidx(int l,int l2,int combo,int lr,int kx,int l1,int m){
  return ((((((l*4+l2)*4+combo)*4+lr)*4+kx)*4+l1)*4+m);
}

__global__ void g_kernel(float* __restrict__ G){
  int tid = threadIdx.x;
  for(int e=tid;e<16384;e+=blockDim.x) G[e]=0.0f;
  __syncthreads();
  int trip = tid >> 4;
  int sub  = tid & 15;
  int lr = sub >> 2, m = sub & 3;
  int idx=0;
  for(int l=0;l<4;l++)for(int l1=0;l1<4;l1++){
    int lo=abs(l-l1), hi=min(3,l+l1);
    for(int l2=lo;l2<=hi;l2++){
      if(idx==trip && lr<=l && m<=l1){
        double c = 8.0*PI_D*PI_D/(2.0*l1+1.0)
                 * sqrt((2.0*l+1.0)*(2.0*l1+1.0)/(4.0*PI_D*(2.0*l2+1.0)))
                 * cg_coef(l,0,l1,0,l2,0);
        if(lr+m<=l2){
          float f = (float)(c * cg_coef(l,lr,l1,m,l2,lr+m) * ((m&1)?-1.0:1.0));
          G[gidx(l,l2,0,lr,lr+m,l1,m)] += f;
          G[gidx(l,l2,1,lr,lr+m,l1,m)] -= f;
          G[gidx(l,l2,2,lr,lr+m,l1,m)] += f;
          G[gidx(l,l2,3,lr,lr+m,l1,m)] += f;
        }
        if(m>0 && abs(lr-m)<=l2){
          if(lr-m>=0){
            float f = (float)(c * cg_coef(l,lr,l1,-m,l2,lr-m) * ((l1&1)?-1.0:1.0));
            G[gidx(l,l2,0,lr,lr-m,l1,m)] += f;
            G[gidx(l,l2,1,lr,lr-m,l1,m)] += f;
            G[gidx(l,l2,2,lr,lr-m,l1,m)] -= f;
            G[gidx(l,l2,3,lr,lr-m,l1,m)] += f;
          } else {
            float f = (float)(c * (((m-lr)&1)?-1.0:1.0) * (((l1+l2)&1)?-1.0:1.0)
                              * cg_coef(l,lr,l1,-m,l2,lr-m));
            G[gidx(l,l2,0,lr,m-lr,l1,m)] += f;
            G[gidx(l,l2,1,lr,m-lr,l1,m)] -= f;
            G[gidx(l,l2,2,lr,m-lr,l1,m)] -= f;
            G[gidx(l,l2,3,lr,m-lr,l1,m)] -= f;
          }
        }
      }
      idx++;
    }
  }
}

__device__ __forceinline__ void decode_kb(int kb,int& l2,int& partp,int& kx,int& t){
  int kbo;
  if(kb<30){l2=0;kbo=0;} else if(kb<90){l2=1;kbo=30;} else if(kb<180){l2=2;kbo=90;} else {l2=3;kbo=180;}
  int rem = kb-kbo;
  int per = (l2+1)*15;
  partp = rem/per;
  int q = rem%per;
  kx = q/15; t = q%15;
}

__device__ __forceinline__ void decode_col(int col,int& l,int& part,int& lr,int& j){
  int co;
  if(col<32){l=0;co=0;} else if(col<96){l=1;co=32;} else if(col<192){l=2;co=96;} else {l=3;co=192;}
  int cr = col-co; int per=(l+1)*16;
  part = cr/per; int q = cr%per; lr = q>>4; j = q&15;
}

// W2: fragment-major bf16. e = (((p*20+cw)*75+kt)*2+ks)*512 + lane*8 + b8
__global__ void w2_kernel(const float* __restrict__ G, Ptrs8 wp, ushort* __restrict__ W2){
  long e = (long)blockIdx.x*256 + threadIdx.x;
  if(e >= 7680000L) return;
  int b8 = (int)(e & 7);
  int ln = (int)((e>>3) & 63);
  int ks = (int)((e>>9) & 1);
  int kt = (int)((e>>10) % 75);
  long rr = (e>>10) / 75;            // p*20+cw
  int cw = (int)(rr % 20);
  int p  = (int)(rr / 20);
  int col = cw*16 + (ln&15);
  int K = kt*64 + ks*32 + ((ln>>4)<<3) + b8;
  int i = K & 15; int kb = K >> 4;
  int l2,partp,kx,t; decode_kb(kb,l2,partp,kx,t);
  int l,part,lr,j; decode_col(col,l,part,lr,j);
  int combo = (part==0) ? (partp==0?0:1) : (partp==0?2:3);
  int wpart = (combo==0||combo==3)?0:1;
  int mstart = wpart?1:0;
  int woff = t*1280 + p*256 + i*16 + j;
  float acc=0.f;
  for(int l1=0;l1<4;l1++){
    const float* wptr = wp.p[l1*2+wpart];
    int gb = ((((l*4+l2)*4+combo)*4+lr)*4+kx)*16 + l1*4;
    for(int m=mstart;m<=l1;m++){
      float g = G[gb+m];
      if(g!=0.f) acc += g * wptr[m*19200 + woff];
    }
  }
  W2[e] = f2bf(acc);
}

// ---------------- pack v2: block = (nb, 15-kt group); CONTIGUOUS tile writes -
// grid 640 = 128 nb x 5 ktg; 512 thr. Per kt: read 64 rows x 4 kb x 320-B runs
// (fp32, activation-friendly), cvt->bf16 into padded LDS (row 680B, p 136B),
// then write complete 8-KB tiles sequentially (slot-swizzle baked for gemm).
__global__ __launch_bounds__(512,3) void pack_nb(Ptrs8 xp, char* __restrict__ Xp5){
  __shared__ ushort L[21760];        // 64 rows x 680 B
  __shared__ int4 KTB[300];          // kb -> {ptr_lo, ptr_hi, byte_off, byte_nstride}
  const int tid = threadIdx.x;
  const int nb  = blockIdx.x & 127;
  const int ktg = blockIdx.x >> 7;   // 0..4
  const int n0 = nb*64;

  for(int e=tid; e<300; e+=512){
    int l2,partp,kx,t; decode_kb(e,l2,partp,kx,t);
    const float* bptr = xp.p[l2*2+partp];
    KTB[e] = make_int4((int)(uint)(unsigned long long)bptr,
                       (int)((unsigned long long)bptr>>32),
                       ((t*(l2+1)+kx)*80)*4, (1200*(l2+1))*4);
  }
  __syncthreads();

  #pragma unroll 1
  for(int ktl=0; ktl<15; ++ktl){
    const int kt = ktg*15 + ktl;
    // load fp32 (coalesced 320-B runs), convert, scatter to padded LDS
    #pragma unroll
    for(int c=0;c<10;++c){
      int g = c*512 + tid;           // < 5120 = 64 rows x 80 units
      int row = g/80; int q = g - row*80;
      int kb_l = q/20; int r20 = q - kb_l*20;
      int p = r20>>2, i4 = r20&3;
      int4 tb = KTB[kt*4 + kb_l];
      const char* src = (const char*)(((unsigned long long)(uint)tb.x) |
                                      ((unsigned long long)(uint)tb.y<<32))
                      + (long)(n0+row)*tb.w + tb.z + p*64 + i4*16;
      float4 v = *(const float4*)src;
      uint2 d;
      d.x = (uint)f2bf(v.x) | ((uint)f2bf(v.y)<<16);
      d.y = (uint)f2bf(v.z) | ((uint)f2bf(v.w)<<16);
      *(uint2*)((char*)L + row*680 + p*136 + kb_l*32 + i4*8) = d;
    }
    __syncthreads();
    // drain: 5 p x 8-KB tiles, fully sequential writes, swizzle baked
    #pragma unroll
    for(int c=0;c<5;++c){
      int g = c*512 + tid;           // < 2560
      int p = g>>9, rem = g&511, row = rem>>3, c8 = rem&7;
      uint4 s = *(const uint4*)((const char*)L + row*680 + p*136 + c8*16);
      *(uint4*)(Xp5 + ((long)(p*128+nb)*75 + kt)*8192 + row*128 + ((c8 ^ (row&7))<<4)) = s;
    }
    __syncthreads();
  }
}

// ---------------- GEMM: all loads coalesced (R13-proven) ---------------------
__device__ __forceinline__ void b_load2(const ushort* Wt,int lane,int kt,short8* b){
  #pragma unroll
  for(int ni=0;ni<5;++ni)
    #pragma unroll
    for(int ks=0;ks<2;++ks)
      b[ks*5+ni] = *(const short8*)(Wt + (long)ni*76800 + kt*1024 + ks*512 + lane*8);
}

__device__ __forceinline__ void do_mfma_f(const ushort* A,int lane,const short8* b,f32x4 acc[4][5]){
  #pragma unroll
  for(int ks=0;ks<2;++ks){
    short8 af[4];
    #pragma unroll
    for(int mi=0;mi<4;++mi){
      int row = mi*16 + (lane&15);
      int kc = ks*4 + (lane>>4);
      af[mi] = *(const short8*)(A + row*64 + ((kc ^ (row&7))<<3));
    }
    #pragma unroll
    for(int mi=0;mi<4;++mi)
      #pragma unroll
      for(int ni=0;ni<5;++ni)
        acc[mi][ni] = __builtin_amdgcn_mfma_f32_16x16x32_bf16(af[mi], b[ks*5+ni], acc[mi][ni], 0,0,0);
  }
}

__global__ __launch_bounds__(256,2) void gemm_f(const char* __restrict__ Xp5,
                                                const ushort* __restrict__ W2,
                                                Ptrs8 bp, float* __restrict__ out){
  __shared__ ushort As[2][4096];
  const int tid = threadIdx.x;
  const int lane = tid & 63;
  const int w = tid >> 6;
  int orig = blockIdx.x;
  int xcd = orig & 7, q = orig >> 3;      // q in [0,80)
  const int p = q / 16;
  const int nb = xcd*16 + (q % 16);
  const int n0 = nb*64;
  const char* At = Xp5 + ((long)(p*128 + nb)*75)*8192;
  const ushort* Wt = W2 + (long)(p*20 + w*5)*76800;

  f32x4 acc[4][5] = {};
  uint4 sA0, sA1;
  short8 bfr[10];

  sA0 = *(const uint4*)(At + tid*16);
  sA1 = *(const uint4*)(At + 4096 + tid*16);
  *(uint4*)(&As[0][tid*8]) = sA0;
  *(uint4*)(&As[0][2048 + tid*8]) = sA1;
  b_load2(Wt, lane, 0, bfr);
  __syncthreads();

  int buf = 0;
  #pragma unroll 1
  for(int kt=0;kt<74;++kt){
    sA0 = *(const uint4*)(At + (kt+1)*8192 + tid*16);
    sA1 = *(const uint4*)(At + (kt+1)*8192 + 4096 + tid*16);
    do_mfma_f(&As[buf][0], lane, bfr, acc);
    b_load2(Wt, lane, kt+1, bfr);
    *(uint4*)(&As[buf^1][tid*8]) = sA0;
    *(uint4*)(&As[buf^1][2048 + tid*8]) = sA1;
    __syncthreads();
    buf ^= 1;
  }
  do_mfma_f(&As[buf][0], lane, bfr, acc);

  int j = lane & 15, rg = (lane>>4)*4;
  #pragma unroll
  for(int ni=0;ni<5;++ni){
    int col16 = w*5 + ni;
    int l, part, lr;
    if(col16<2){l=0;part=col16;lr=0;}
    else if(col16<6){int c=col16-2;l=1;part=c>>1;lr=c&1;}
    else if(col16<12){int c=col16-6;l=2;part=(c>=3);lr=part?(c-3):c;}
    else {int c=col16-12;l=3;part=c>>2;lr=c&3;}
    float bv = 0.f;
    if(!(part==1 && lr==0)) bv = bp.p[l*2+part][lr*80 + p*16 + j];
    long base = 655360L*(l+1)*(l+part);
    int nst = (l+1)*80;
    long ioff = base + lr*80 + p*16 + j;
    #pragma unroll
    for(int mi=0;mi<4;++mi){
      int n = n0 + mi*16 + rg;
      #pragma unroll
      for(int r=0;r<4;++r)
        out[ioff + (long)(n+r)*nst] = acc[mi][ni][r] + bv;
    }
  }
}

// ---------------- fallback (direct-from-x; uses W2 fragment layout) ----------
__device__ __forceinline__ void a_load(const Ptrs8& xp, int p, int n0, int kt, int w, int lane, float4* v){
  int kb = kt*4 + w;
  int l2,partp,kx,t; decode_kb(kb,l2,partp,kx,t);
  const float* xb = xp.p[l2*2+partp];
  int nstr = 1200*(l2+1);
  const float* base = xb + (long)(n0 + (lane>>2))*nstr + (t*(l2+1)+kx)*80 + p*16 + (lane&3)*4;
  long step = (long)16*nstr;
  #pragma unroll
  for(int s=0;s<4;++s) v[s] = *(const float4*)(base + s*step);
}

__device__ __forceinline__ void a_store(ushort* As, int w, int lane, const float4* v){
  int rsub = lane>>2, c4 = (lane&3)*4;
  #pragma unroll
  for(int s=0;s<4;++s){
    int row = s*16 + rsub;
    int e = row*64 + ((w*16 + c4) ^ ((row&7)<<3));
    uint2 d;
    d.x = (uint)f2bf(v[s].x) | ((uint)f2bf(v[s].y)<<16);
    d.y = (uint)f2bf(v[s].z) | ((uint)f2bf(v[s].w)<<16);
    *(uint2*)(As + e) = d;
  }
}

__device__ __forceinline__ void do_mfma64(const ushort* As, int lane, const short8* b, f32x4 acc[4][5]){
  #pragma unroll
  for(int ks=0;ks<2;++ks){
    short8 af[4];
    #pragma unroll
    for(int mi=0;mi<4;++mi){
      int row = mi*16 + (lane&15);
      int e = row*64 + (((ks*32) + (lane>>4)*8) ^ ((row&7)<<3));
      af[mi] = *(const short8*)(As + e);
    }
    #pragma unroll
    for(int mi=0;mi<4;++mi)
      #pragma unroll
      for(int ni=0;ni<5;++ni)
        acc[mi][ni] = __builtin_amdgcn_mfma_f32_16x16x32_bf16(af[mi], b[ks*5+ni], acc[mi][ni], 0,0,0);
  }
}

__global__ __launch_bounds__(256,2) void gemm_direct(Ptrs8 xp, const ushort* __restrict__ W2,
                                                     Ptrs8 bp, float* __restrict__ out){
  __shared__ ushort As[2][4096];
  const int tid = threadIdx.x;
  const int lane = tid & 63;
  const int w = tid >> 6;
  int orig = blockIdx.x;
  int x = orig & 7, q = orig >> 3;
  const int p = q % 5;
  const int nb = (q/5)*8 + x;
  const int n0 = nb*64;
  const ushort* Wt = W2 + (long)(p*20 + w*5)*76800;

  f32x4 acc[4][5] = {};
  float4 av[4];
  short8 bfr[10];

  a_load(xp, p, n0, 0, w, lane, av);
  a_store(&As[0][0], w, lane, av);
  b_load2(Wt, lane, 0, bfr);
  __syncthreads();

  int buf = 0;
  #pragma unroll 1
  for(int kt=0;kt<74;++kt){
    a_load(xp, p, n0, kt+1, w, lane, av);
    do_mfma64(&As[buf][0], lane, bfr, acc);
    b_load2(Wt, lane, kt+1, bfr);
    a_store(&As[buf^1][0], w, lane, av);
    __syncthreads();
    buf ^= 1;
  }
  do_mfma64(&As[buf][0], lane, bfr, acc);

  int j = lane & 15, rg = (lane>>4)*4;
  #pragma unroll
  for(int ni=0;ni<5;++ni){
    int col16 = w*5 + ni;
    int l, part, lr;
    if(col16<2){l=0;part=col16;lr=0;}
    else if(col16<6){int c=col16-2;l=1;part=c>>1;lr=c&1;}
    else if(col16<12){int c=col16-6;l=2;part=(c>=3);lr=part?(c-3):c;}
    else {int c=col16-12;l=3;part=c>>2;lr=c&3;}
    float bv = 0.f;
    if(!(part==1 && lr==0)) bv = bp.p[l*2+part][lr*80 + p*16 + j];
    long base = 655360L*(l+1)*(l+part);
    int nst = (l+1)*80;
    long ioff = base + lr*80 + p*16 + j;
    #pragma unroll
    for(int mi=0;mi<4;++mi){
      int n = n0 + mi*16 + rg;
      #pragma unroll
      for(int r=0;r<4;++r)
        out[ioff + (long)(n+r)*nst] = acc[mi][ni][r] + bv;
    }
  }
}

extern "C" void kernel_launch(void* const* d_in, const int* in_sizes, int n_in,
                              void* d_out, int out_size, void* d_ws, size_t ws_size,
                              hipStream_t stream){
  Ptrs8 xp, wp, bp;
  for(int i=0;i<8;i++){
    xp.p[i] = (const float*)d_in[i];
    wp.p[i] = (const float*)d_in[8+i];
    bp.p[i] = (const float*)d_in[16+i];
  }
  float* G = (float*)d_ws;
  ushort* W2 = (ushort*)((char*)d_ws + 65536);
  g_kernel<<<dim3(1), dim3(576), 0, stream>>>(G);
  w2_kernel<<<dim3(30000), dim3(256), 0, stream>>>(G, wp, W2);
  const size_t need = 16777216ull + 393216000ull;
  if(ws_size >= need){
    char* Xp5 = (char*)d_ws + 16777216;
    pack_nb<<<dim3(640), dim3(512), 0, stream>>>(xp, Xp5);
    gemm_f<<<dim3(640), dim3(256), 0, stream>>>(Xp5, W2, bp, (float*)d_out);
  } else {
    gemm_direct<<<dim3(640), dim3(256), 0, stream>>>(xp, W2, bp, (float*)d_out);
  }
}